// Round 3
// baseline (560.399 us; speedup 1.0000x reference)
//
#include <hip/hip_runtime.h>
#include <hip/hip_bf16.h>
#include <math.h>

#define IMG 224
#define PIX (IMG*IMG)   // 50176
#define B_ 32
#define E_ 512
#define N_ 4096
#define SV_BLOCKS 256
#define SC_ ((float)(512.0/224.0))
#define RPB 16          // rows per stats block
#define NCHUNK 32       // E_/RPB
#define NT2 3           // 128x128 tiles covering upper triangle of 224x224
#define LDSTR2 72

typedef __attribute__((ext_vector_type(8))) short bf16x8;
typedef __attribute__((ext_vector_type(4))) float f32x4;

__device__ inline unsigned short f2bf(float f){
  unsigned u = __float_as_uint(f);
  unsigned r = (u + 0x7FFFu + ((u >> 16) & 1u)) >> 16;  // RNE
  return (unsigned short)r;
}

// ---------- fused: row stats + column partials + inline y emission ----------
__global__ void __launch_bounds__(256) stats_y(const float* __restrict__ x,
                                               float* __restrict__ meanv,
                                               float* __restrict__ colpart,
                                               ushort* __restrict__ y){
  int b = blockIdx.x >> 5, chunk = blockIdx.x & 31;
  int e0 = chunk << 4;
  int t = threadIdx.x;
  __shared__ short sInv[512];   // src row r0 -> output row i (or -1)
  __shared__ float sW[224];     // interp weight per output row
  __shared__ float red[2][16];  // parity-buffered reduction slab
  sInv[t] = -1; sInv[t + 256] = -1;
  __syncthreads();
  if (t < 224){
    float r = fmaxf(((float)t + 0.5f) * SC_ - 0.5f, 0.f);
    int r0 = min((int)r, E_ - 1);
    sW[t] = r - (float)r0;
    sInv[r0] = (short)t;        // scale > 2 => at most one i per r0
  }
  __syncthreads();

  float cur[16], prev[16], nxt[16], csum[16];
  #pragma unroll
  for (int j = 0; j < 16; j++){ csum[j] = 0.f; prev[j] = 0.f; }
  const float4* row0 = (const float4*)(x + ((size_t)b * E_ + e0) * N_);
  #pragma unroll
  for (int k = 0; k < 4; k++) *(float4*)(cur + 4 * k) = row0[t + 256 * k];
  float pmu = 0.f, prn = 0.f;

  for (int idx = 0; idx <= RPB; idx++){
    int e = e0 + idx;
    if (e >= E_) break;
    bool hasNext = (idx < RPB) && (e + 1 < E_);
    if (hasNext){
      const float4* nr = (const float4*)(x + ((size_t)b * E_ + e + 1) * N_);
      #pragma unroll
      for (int k = 0; k < 4; k++) *(float4*)(nxt + 4 * k) = nr[t + 256 * k];
    }
    float s = 0.f, ss = 0.f;
    #pragma unroll
    for (int j = 0; j < 16; j++){ s += cur[j]; ss += cur[j] * cur[j]; }
    #pragma unroll
    for (int o = 32; o; o >>= 1){ s += __shfl_down(s, o); ss += __shfl_down(ss, o); }
    int wv = t >> 6, ln = t & 63, p = idx & 1;
    if (ln == 0){ red[p][wv] = s; red[p][8 + wv] = ss; }
    __syncthreads();    // single barrier per row
    float S  = red[p][0] + red[p][1] + red[p][2] + red[p][3];
    float SS = red[p][8] + red[p][9] + red[p][10] + red[p][11];
    float mu = S * (1.f / N_);
    float var = fmaxf(SS - S * S * (1.f / N_), 0.f);
    float rn = 1.f / (sqrtf(var) + 1e-8f);
    if (idx < RPB){
      #pragma unroll
      for (int j = 0; j < 16; j++) csum[j] += cur[j];
      if (t == 0) meanv[b * E_ + e] = mu;
    }
    if (idx >= 1){
      int i = sInv[e - 1];
      if (i >= 0){
        float w = sW[i];
        float a0 = (1.f - w) * prn, a1 = w * rn;
        float cc = -(a0 * pmu + a1 * mu);
        ushort* yo = y + ((size_t)b * IMG + i) * N_;
        #pragma unroll
        for (int k = 0; k < 4; k++){
          union { ushort u[4]; int2 v; } pk;
          #pragma unroll
          for (int j = 0; j < 4; j++)
            pk.u[j] = f2bf(a0 * prev[4*k+j] + a1 * cur[4*k+j] + cc);
          *(int2*)(yo + 1024 * k + 4 * t) = pk.v;
        }
      }
    }
    pmu = mu; prn = rn;
    #pragma unroll
    for (int j = 0; j < 16; j++){ prev[j] = cur[j]; if (hasNext) cur[j] = nxt[j]; }
  }
  float* cp = colpart + ((size_t)(b * NCHUNK + chunk)) * N_;
  #pragma unroll
  for (int k = 0; k < 4; k++) *(float4*)(cp + 1024 * k + 4 * t) = *(float4*)(csum + 4 * k);
}

// colmean[b][n] = (1/E) * sum of 32 partials
__global__ void __launch_bounds__(256) col_finalize(const float* __restrict__ colpart,
                                                    float* __restrict__ colmean){
  int b = blockIdx.x >> 4;
  int n = ((blockIdx.x & 15) << 8) + threadIdx.x;
  float s = 0.f;
  #pragma unroll
  for (int c = 0; c < NCHUNK; c++) s += colpart[((size_t)(b * NCHUNK + c)) * N_ + n];
  colmean[b * N_ + n] = s * (1.f / E_);
}

// ---------------- small views (temporal + spatial) ------------------------
__device__ inline float grid_val(const float* v, int gs, int n, int r, int c){
  int idx = r * gs + c;
  return (idx < n) ? v[idx] : 0.f;
}
__device__ inline float bilin(const float* v, int gs, int n, int i, int j){
  float sc = (float)((double)gs / 224.0);
  float r = fmaxf(((float)i + 0.5f) * sc - 0.5f, 0.f);
  float c = fmaxf(((float)j + 0.5f) * sc - 0.5f, 0.f);
  int r0 = min((int)r, gs - 1), c0 = min((int)c, gs - 1);
  int r1 = min(r0 + 1, gs - 1), c1 = min(c0 + 1, gs - 1);
  float wr = r - (float)r0, wc = c - (float)c0;
  float v00 = grid_val(v, gs, n, r0, c0), v10 = grid_val(v, gs, n, r1, c0);
  float v01 = grid_val(v, gs, n, r0, c1), v11 = grid_val(v, gs, n, r1, c1);
  float ra = v00 * (1.f - wr) + v10 * wr;
  float rb = v01 * (1.f - wr) + v11 * wr;
  return ra * (1.f - wc) + rb * wc;
}

// store-free pass: min/max of the two resized small views (grids are L2-resident)
__global__ void __launch_bounds__(256) sv_minmax(const float* __restrict__ meanv,
                                                 const float* __restrict__ colmean,
                                                 float* __restrict__ scr){
  float tmn = INFINITY, tmx = -INFINITY, smn = INFINITY, smx = -INFINITY;
  for (int g = blockIdx.x * 256 + threadIdx.x; g < B_ * PIX; g += SV_BLOCKS * 256){
    int b = g / PIX, p = g - b * PIX;
    int i = p / IMG, j = p - i * IMG;
    float tv = bilin(meanv   + b * E_, 23, E_, i, j);
    float sv = bilin(colmean + b * N_, 64, N_, i, j);
    tmn = fminf(tmn, tv); tmx = fmaxf(tmx, tv);
    smn = fminf(smn, sv); smx = fmaxf(smx, sv);
  }
  #pragma unroll
  for (int o = 32; o; o >>= 1){
    tmn = fminf(tmn, __shfl_down(tmn, o)); tmx = fmaxf(tmx, __shfl_down(tmx, o));
    smn = fminf(smn, __shfl_down(smn, o)); smx = fmaxf(smx, __shfl_down(smx, o));
  }
  __shared__ float red[4][4];
  int wv = threadIdx.x >> 6, ln = threadIdx.x & 63;
  if (ln == 0){ red[wv][0] = tmn; red[wv][1] = tmx; red[wv][2] = smn; red[wv][3] = smx; }
  __syncthreads();
  if (threadIdx.x == 0){
    scr[blockIdx.x * 4 + 0] = fminf(fminf(red[0][0], red[1][0]), fminf(red[2][0], red[3][0]));
    scr[blockIdx.x * 4 + 1] = fmaxf(fmaxf(red[0][1], red[1][1]), fmaxf(red[2][1], red[3][1]));
    scr[blockIdx.x * 4 + 2] = fminf(fminf(red[0][2], red[1][2]), fminf(red[2][2], red[3][2]));
    scr[blockIdx.x * 4 + 3] = fmaxf(fmaxf(red[0][3], red[1][3]), fmaxf(red[2][3], red[3][3]));
  }
}

// ---------------- correlation GEMM: fused 128x128 tiles, full K -----------
// grid = B*NT2 = 96 blocks. Tiles (ti,tj) in {(0,0),(0,1),(1,1)} of 128x128.
// Double-buffered LDS + one-step register prefetch; epilogue writes C (+mirror)
// and per-block minmax -> scr. One barrier per K-step (dbuf makes 2nd redundant).
__device__ const int TI2_[NT2] = {0, 0, 1};
__device__ const int TJ2_[NT2] = {0, 1, 1};

__global__ void __launch_bounds__(256) corr_gemm_f(const ushort* __restrict__ y,
                                                   float* __restrict__ out,
                                                   float* __restrict__ scr){
  int b = blockIdx.x / NT2, tile = blockIdx.x - b * NT2;
  int ti = TI2_[tile], tj = TJ2_[tile];
  bool diag = (ti == tj);
  const ushort* yb = y + (size_t)b * IMG * N_;
  __shared__ ushort lA[2][128 * LDSTR2];
  __shared__ ushort lB[2][128 * LDSTR2];
  int t = threadIdx.x;
  int wv = t >> 6, ln = t & 63;
  int wm = wv & 1, wn = wv >> 1;
  int quad = ln >> 4, l16 = ln & 15;
  int s8 = t & 7, r0 = t >> 3;   // int4 slot within row, base row 0..31
  f32x4 acc[4][4] = {};
  int rA[4], rB[4];
  #pragma unroll
  for (int q = 0; q < 4; q++){
    rA[q] = min(ti * 128 + r0 + 32 * q, IMG - 1);  // clamp: dup rows never stored
    rB[q] = min(tj * 128 + r0 + 32 * q, IMG - 1);
  }
  int4 ra[4], rb[4];
  #pragma unroll
  for (int q = 0; q < 4; q++){
    ra[q] = *(const int4*)(yb + (size_t)rA[q] * N_ + s8 * 8);
    rb[q] = *(const int4*)(yb + (size_t)rB[q] * N_ + s8 * 8);
  }
  for (int s = 0; s < 64; s++){
    int cur = s & 1;
    #pragma unroll
    for (int q = 0; q < 4; q++){
      *(int4*)(lA[cur] + (r0 + 32 * q) * LDSTR2 + s8 * 8) = ra[q];
      *(int4*)(lB[cur] + (r0 + 32 * q) * LDSTR2 + s8 * 8) = rb[q];
    }
    if (s + 1 < 64){
      int k0 = (s + 1) * 64;
      #pragma unroll
      for (int q = 0; q < 4; q++){
        ra[q] = *(const int4*)(yb + (size_t)rA[q] * N_ + k0 + s8 * 8);
        rb[q] = *(const int4*)(yb + (size_t)rB[q] * N_ + k0 + s8 * 8);
      }
    }
    __syncthreads();
    #pragma unroll
    for (int kk = 0; kk < 2; kk++){
      bf16x8 af[4], bf[4];
      #pragma unroll
      for (int m = 0; m < 4; m++){
        af[m] = *(const bf16x8*)(lA[cur] + (wm * 64 + m * 16 + l16) * LDSTR2 + kk * 32 + quad * 8);
        bf[m] = *(const bf16x8*)(lB[cur] + (wn * 64 + m * 16 + l16) * LDSTR2 + kk * 32 + quad * 8);
      }
      #pragma unroll
      for (int im = 0; im < 4; im++)
        #pragma unroll
        for (int in = 0; in < 4; in++)
          acc[im][in] = __builtin_amdgcn_mfma_f32_16x16x32_bf16(af[im], bf[in], acc[im][in], 0, 0, 0);
    }
  }
  // epilogue: write C (+ mirror for off-diag), per-block minmax
  float mn = INFINITY, mx = -INFINITY;
  float* ov = out + ((size_t)b * 3 + 2) * PIX;
  #pragma unroll
  for (int im = 0; im < 4; im++){
    #pragma unroll
    for (int in = 0; in < 4; in++){
      int gi0 = ti * 128 + wm * 64 + im * 16 + quad * 4;
      int gj  = tj * 128 + wn * 64 + in * 16 + l16;
      #pragma unroll
      for (int rg = 0; rg < 4; rg++){
        int gi = gi0 + rg;
        if (gi < IMG && gj < IMG){
          float v = acc[im][in][rg];
          ov[gi * IMG + gj] = v;
          mn = fminf(mn, v); mx = fmaxf(mx, v);
        }
      }
      if (!diag && gj < IMG && gi0 < IMG){   // mirrored tile, packed store
        float4 tv;
        tv.x = acc[im][in][0]; tv.y = acc[im][in][1];
        tv.z = acc[im][in][2]; tv.w = acc[im][in][3];
        *(float4*)(ov + gj * IMG + gi0) = tv;
      }
    }
  }
  #pragma unroll
  for (int o = 32; o; o >>= 1){
    mn = fminf(mn, __shfl_down(mn, o)); mx = fmaxf(mx, __shfl_down(mx, o));
  }
  __shared__ float red[4][2];
  if (ln == 0){ red[wv][0] = mn; red[wv][1] = mx; }
  __syncthreads();
  if (t == 0){
    scr[blockIdx.x * 2 + 0] = fminf(fminf(red[0][0], red[1][0]), fminf(red[2][0], red[3][0]));
    scr[blockIdx.x * 2 + 1] = fmaxf(fmaxf(red[0][1], red[1][1]), fmaxf(red[2][1], red[3][1]));
  }
}

// ---------------- final minmax reduce ---------------------------------------
__global__ void __launch_bounds__(256) reduce_slots(const float* __restrict__ sv_scr,
                                                    const float* __restrict__ corr_scr,
                                                    float* __restrict__ slots){
  int t = threadIdx.x;
  float tmn = sv_scr[4*t+0], tmx = sv_scr[4*t+1];
  float smn = sv_scr[4*t+2], smx = sv_scr[4*t+3];
  float cmn = INFINITY, cmx = -INFINITY;
  for (int idx = t; idx < B_ * NT2; idx += 256){
    cmn = fminf(cmn, corr_scr[2*idx]);
    cmx = fmaxf(cmx, corr_scr[2*idx+1]);
  }
  #pragma unroll
  for (int o = 32; o; o >>= 1){
    tmn = fminf(tmn, __shfl_down(tmn, o)); tmx = fmaxf(tmx, __shfl_down(tmx, o));
    smn = fminf(smn, __shfl_down(smn, o)); smx = fmaxf(smx, __shfl_down(smx, o));
    cmn = fminf(cmn, __shfl_down(cmn, o)); cmx = fmaxf(cmx, __shfl_down(cmx, o));
  }
  __shared__ float red[4][6];
  int wv = t >> 6, ln = t & 63;
  if (ln == 0){
    red[wv][0]=tmn; red[wv][1]=tmx; red[wv][2]=smn;
    red[wv][3]=smx; red[wv][4]=cmn; red[wv][5]=cmx;
  }
  __syncthreads();
  if (t == 0){
    slots[0] = fminf(fminf(red[0][0],red[1][0]), fminf(red[2][0],red[3][0]));
    slots[1] = fmaxf(fmaxf(red[0][1],red[1][1]), fmaxf(red[2][1],red[3][1]));
    slots[2] = fminf(fminf(red[0][2],red[1][2]), fminf(red[2][2],red[3][2]));
    slots[3] = fmaxf(fmaxf(red[0][3],red[1][3]), fmaxf(red[2][3],red[3][3]));
    slots[4] = fminf(fminf(red[0][4],red[1][4]), fminf(red[2][4],red[3][4]));
    slots[5] = fmaxf(fmaxf(red[0][5],red[1][5]), fmaxf(red[2][5],red[3][5]));
  }
}

// ---------------- final: recompute small views normalized + normalize corr ---
__global__ void __launch_bounds__(256) final_write(const float* __restrict__ meanv,
                                                   const float* __restrict__ colmean,
                                                   float* __restrict__ out,
                                                   const float* __restrict__ slots){
  int g = blockIdx.x * 256 + threadIdx.x;
  float tmn = slots[0], tmx = slots[1];
  float smn = slots[2], smx = slots[3];
  int b = g / PIX, p = g - b * PIX;
  int i = p / IMG, j = p - i * IMG;
  float tv = bilin(meanv   + b * E_, 23, E_, i, j);
  float sv = bilin(colmean + b * N_, 64, N_, i, j);
  float td = tmx - tmn, sd = smx - smn;
  out[((size_t)b * 3 + 0) * PIX + p] = (td < 1e-8f) ? 0.f : (tv - tmn) / (td + 1e-8f);
  out[((size_t)b * 3 + 1) * PIX + p] = (sd < 1e-8f) ? 0.f : (sv - smn) / (sd + 1e-8f);
  if (g < B_ * PIX / 4){           // uniform per block: B*PIX/4 = 1568*256
    float cmn = slots[4], cmx = slots[5];
    float cd = cmx - cmn;
    float inv = 1.f / (cd + 1e-8f);
    bool z = cd < 1e-8f;
    int c = g * 4;
    int bb = c / PIX, pp = c - bb * PIX;   // PIX % 4 == 0 -> uniform bb in float4
    float* oc = out + ((size_t)bb * 3 + 2) * PIX + pp;
    float4 v = *(float4*)oc;
    v.x = z ? 0.f : (v.x - cmn) * inv;
    v.y = z ? 0.f : (v.y - cmn) * inv;
    v.z = z ? 0.f : (v.z - cmn) * inv;
    v.w = z ? 0.f : (v.w - cmn) * inv;
    *(float4*)oc = v;
  }
}

extern "C" void kernel_launch(void* const* d_in, const int* in_sizes, int n_in,
                              void* d_out, int out_size, void* d_ws, size_t ws_size,
                              hipStream_t stream){
  const float* x = (const float*)d_in[0];
  float* out = (float*)d_out;
  char* ws = (char*)d_ws;
  float* slots    = (float*)(ws + 0);                     // 6 f (pad 256 B)
  float* meanv    = (float*)(ws + 256);                   // B*E f
  float* colmean  = meanv + B_ * E_;                      // B*N f
  float* colpart  = colmean + B_ * N_;                    // B*32*N f (16 MB)
  float* sv_scr   = colpart + (size_t)B_ * NCHUNK * N_;   // SV_BLOCKS*4 f
  float* corr_scr = sv_scr + SV_BLOCKS * 4;               // 192 f
  size_t y_off = ((size_t)((char*)(corr_scr + B_ * NT2 * 2) - ws) + 255) & ~(size_t)255;
  ushort* y = (ushort*)(ws + y_off);                      // B*224*4096 bf16 (58.7 MB)

  hipLaunchKernelGGL(stats_y, dim3(B_ * NCHUNK), dim3(256), 0, stream,
                     x, meanv, colpart, y);
  hipLaunchKernelGGL(corr_gemm_f, dim3(B_ * NT2), dim3(256), 0, stream,
                     y, out, corr_scr);
  hipLaunchKernelGGL(col_finalize, dim3(B_ * 16), dim3(256), 0, stream,
                     colpart, colmean);
  hipLaunchKernelGGL(sv_minmax, dim3(SV_BLOCKS), dim3(256), 0, stream,
                     meanv, colmean, sv_scr);
  hipLaunchKernelGGL(reduce_slots, dim3(1), dim3(256), 0, stream,
                     sv_scr, corr_scr, slots);
  hipLaunchKernelGGL(final_write, dim3(B_ * PIX / 256), dim3(256), 0, stream,
                     meanv, colmean, out, slots);
}

// Round 4
// 445.323 us; speedup vs baseline: 1.2584x; 1.2584x over previous
//
#include <hip/hip_runtime.h>
#include <hip/hip_bf16.h>
#include <math.h>

#define IMG 224
#define PIX (IMG*IMG)   // 50176
#define B_ 32
#define E_ 512
#define N_ 4096
#define SV_BLOCKS 256
#define SC_ ((float)(512.0/224.0))
#define RPB 16          // rows per stats block
#define NCHUNK 32       // E_/RPB
#define KSPLIT 2
#define KLEN (N_/KSPLIT)  // 2048
#define NTILE 10          // symmetric 64x64 tiles of 224x224

typedef __attribute__((ext_vector_type(8))) short bf16x8;
typedef __attribute__((ext_vector_type(4))) float f32x4;

__device__ inline unsigned short f2bf(float f){
  unsigned u = __float_as_uint(f);
  unsigned r = (u + 0x7FFFu + ((u >> 16) & 1u)) >> 16;  // RNE
  return (unsigned short)r;
}

// ---------- fused: row stats + column partials + inline y emission ----------
__global__ void __launch_bounds__(256) stats_y(const float* __restrict__ x,
                                               float* __restrict__ meanv,
                                               float* __restrict__ colpart,
                                               ushort* __restrict__ y){
  int b = blockIdx.x >> 5, chunk = blockIdx.x & 31;
  int e0 = chunk << 4;
  int t = threadIdx.x;
  __shared__ short sInv[512];   // src row r0 -> output row i (or -1)
  __shared__ float sW[224];     // interp weight per output row
  __shared__ float red[2][16];  // parity-buffered reduction slab
  sInv[t] = -1; sInv[t + 256] = -1;
  __syncthreads();
  if (t < 224){
    float r = fmaxf(((float)t + 0.5f) * SC_ - 0.5f, 0.f);
    int r0 = min((int)r, E_ - 1);
    sW[t] = r - (float)r0;
    sInv[r0] = (short)t;        // scale > 2 => at most one i per r0
  }
  __syncthreads();

  float cur[16], prev[16], nxt[16], csum[16];
  #pragma unroll
  for (int j = 0; j < 16; j++){ csum[j] = 0.f; prev[j] = 0.f; }
  const float4* row0 = (const float4*)(x + ((size_t)b * E_ + e0) * N_);
  #pragma unroll
  for (int k = 0; k < 4; k++) *(float4*)(cur + 4 * k) = row0[t + 256 * k];
  float pmu = 0.f, prn = 0.f;

  for (int idx = 0; idx <= RPB; idx++){
    int e = e0 + idx;
    if (e >= E_) break;
    bool hasNext = (idx < RPB) && (e + 1 < E_);
    if (hasNext){
      const float4* nr = (const float4*)(x + ((size_t)b * E_ + e + 1) * N_);
      #pragma unroll
      for (int k = 0; k < 4; k++) *(float4*)(nxt + 4 * k) = nr[t + 256 * k];
    }
    float s = 0.f, ss = 0.f;
    #pragma unroll
    for (int j = 0; j < 16; j++){ s += cur[j]; ss += cur[j] * cur[j]; }
    #pragma unroll
    for (int o = 32; o; o >>= 1){ s += __shfl_down(s, o); ss += __shfl_down(ss, o); }
    int wv = t >> 6, ln = t & 63, p = idx & 1;
    if (ln == 0){ red[p][wv] = s; red[p][8 + wv] = ss; }
    __syncthreads();    // single barrier per row
    float S  = red[p][0] + red[p][1] + red[p][2] + red[p][3];
    float SS = red[p][8] + red[p][9] + red[p][10] + red[p][11];
    float mu = S * (1.f / N_);
    float var = fmaxf(SS - S * S * (1.f / N_), 0.f);
    float rn = 1.f / (sqrtf(var) + 1e-8f);
    if (idx < RPB){
      #pragma unroll
      for (int j = 0; j < 16; j++) csum[j] += cur[j];
      if (t == 0) meanv[b * E_ + e] = mu;
    }
    if (idx >= 1){
      int i = sInv[e - 1];
      if (i >= 0){
        float w = sW[i];
        float a0 = (1.f - w) * prn, a1 = w * rn;
        float cc = -(a0 * pmu + a1 * mu);
        ushort* yo = y + ((size_t)b * IMG + i) * N_;
        #pragma unroll
        for (int k = 0; k < 4; k++){
          union { ushort u[4]; int2 v; } pk;
          #pragma unroll
          for (int j = 0; j < 4; j++)
            pk.u[j] = f2bf(a0 * prev[4*k+j] + a1 * cur[4*k+j] + cc);
          *(int2*)(yo + 1024 * k + 4 * t) = pk.v;
        }
      }
    }
    pmu = mu; prn = rn;
    #pragma unroll
    for (int j = 0; j < 16; j++){ prev[j] = cur[j]; if (hasNext) cur[j] = nxt[j]; }
  }
  float* cp = colpart + ((size_t)(b * NCHUNK + chunk)) * N_;
  #pragma unroll
  for (int k = 0; k < 4; k++) *(float4*)(cp + 1024 * k + 4 * t) = *(float4*)(csum + 4 * k);
}

// colmean[b][n] = (1/E) * sum of 32 partials
__global__ void __launch_bounds__(256) col_finalize(const float* __restrict__ colpart,
                                                    float* __restrict__ colmean){
  int b = blockIdx.x >> 4;
  int n = ((blockIdx.x & 15) << 8) + threadIdx.x;
  float s = 0.f;
  #pragma unroll
  for (int c = 0; c < NCHUNK; c++) s += colpart[((size_t)(b * NCHUNK + c)) * N_ + n];
  colmean[b * N_ + n] = s * (1.f / E_);
}

// ---------------- small views (temporal + spatial) ------------------------
__device__ inline float grid_val(const float* v, int gs, int n, int r, int c){
  int idx = r * gs + c;
  return (idx < n) ? v[idx] : 0.f;
}
__device__ inline float bilin(const float* v, int gs, int n, int i, int j){
  float sc = (float)((double)gs / 224.0);
  float r = fmaxf(((float)i + 0.5f) * sc - 0.5f, 0.f);
  float c = fmaxf(((float)j + 0.5f) * sc - 0.5f, 0.f);
  int r0 = min((int)r, gs - 1), c0 = min((int)c, gs - 1);
  int r1 = min(r0 + 1, gs - 1), c1 = min(c0 + 1, gs - 1);
  float wr = r - (float)r0, wc = c - (float)c0;
  float v00 = grid_val(v, gs, n, r0, c0), v10 = grid_val(v, gs, n, r1, c0);
  float v01 = grid_val(v, gs, n, r0, c1), v11 = grid_val(v, gs, n, r1, c1);
  float ra = v00 * (1.f - wr) + v10 * wr;
  float rb = v01 * (1.f - wr) + v11 * wr;
  return ra * (1.f - wc) + rb * wc;
}

// store-free pass: min/max of the two resized small views (grids are L2-resident)
__global__ void __launch_bounds__(256) sv_minmax(const float* __restrict__ meanv,
                                                 const float* __restrict__ colmean,
                                                 float* __restrict__ scr){
  float tmn = INFINITY, tmx = -INFINITY, smn = INFINITY, smx = -INFINITY;
  for (int g = blockIdx.x * 256 + threadIdx.x; g < B_ * PIX; g += SV_BLOCKS * 256){
    int b = g / PIX, p = g - b * PIX;
    int i = p / IMG, j = p - i * IMG;
    float tv = bilin(meanv   + b * E_, 23, E_, i, j);
    float sv = bilin(colmean + b * N_, 64, N_, i, j);
    tmn = fminf(tmn, tv); tmx = fmaxf(tmx, tv);
    smn = fminf(smn, sv); smx = fmaxf(smx, sv);
  }
  #pragma unroll
  for (int o = 32; o; o >>= 1){
    tmn = fminf(tmn, __shfl_down(tmn, o)); tmx = fmaxf(tmx, __shfl_down(tmx, o));
    smn = fminf(smn, __shfl_down(smn, o)); smx = fmaxf(smx, __shfl_down(smx, o));
  }
  __shared__ float red[4][4];
  int wv = threadIdx.x >> 6, ln = threadIdx.x & 63;
  if (ln == 0){ red[wv][0] = tmn; red[wv][1] = tmx; red[wv][2] = smn; red[wv][3] = smx; }
  __syncthreads();
  if (threadIdx.x == 0){
    scr[blockIdx.x * 4 + 0] = fminf(fminf(red[0][0], red[1][0]), fminf(red[2][0], red[3][0]));
    scr[blockIdx.x * 4 + 1] = fmaxf(fmaxf(red[0][1], red[1][1]), fmaxf(red[2][1], red[3][1]));
    scr[blockIdx.x * 4 + 2] = fminf(fminf(red[0][2], red[1][2]), fminf(red[2][2], red[3][2]));
    scr[blockIdx.x * 4 + 3] = fmaxf(fmaxf(red[0][3], red[1][3]), fmaxf(red[2][3], red[3][3]));
  }
}

// ---------------- correlation GEMM: split-K partials -----------------------
// XCD-pinned mapping: blockIdx%8 = XCD (dispatch round-robin). Each XCD owns
// 4 batches x 20 (ks,tile) slots, so a batch's y-panels (1.83 MB) are re-read
// from that XCD's 4 MB L2 instead of L3. 640 = 8*80 exactly -> bijective.
#define LDSTR 72
__device__ const int TI_[NTILE] = {0,0,0,0,1,1,1,2,2,3};
__device__ const int TJ_[NTILE] = {0,1,2,3,1,2,3,2,3,3};

__global__ void __launch_bounds__(256) corr_gemm_sk(const ushort* __restrict__ y,
                                                    float* __restrict__ partials){
  int xcd  = blockIdx.x & 7;
  int slot = blockIdx.x >> 3;          // 0..79 within this XCD
  int b    = (xcd << 2) + (slot / 20); // 4 batches per XCD
  int rem  = slot % 20;
  int ks   = rem / 10;
  int tile = rem - ks * 10;
  int bt   = b * NTILE + tile;
  int ti = TI_[tile], tj = TJ_[tile];
  const ushort* yb = y + (size_t)b * IMG * N_ + (size_t)ks * KLEN;
  __shared__ ushort lA[64 * LDSTR];
  __shared__ ushort lB[64 * LDSTR];
  int t = threadIdx.x;
  int wv = t >> 6, ln = t & 63;
  int wm = wv & 1, wn = wv >> 1;
  int quad = ln >> 4, l16 = ln & 15;
  f32x4 acc[2][2] = {};
  int s = t & 7, r2 = t >> 3;
  int rA0 = min(ti * 64 + r2,      223), rA1 = min(ti * 64 + r2 + 32, 223);
  int rB0 = min(tj * 64 + r2,      223), rB1 = min(tj * 64 + r2 + 32, 223);
  for (int k0 = 0; k0 < KLEN; k0 += 64){
    int4 a0 = *(const int4*)(yb + (size_t)rA0 * N_ + k0 + s * 8);
    int4 a1 = *(const int4*)(yb + (size_t)rA1 * N_ + k0 + s * 8);
    int4 b0v = *(const int4*)(yb + (size_t)rB0 * N_ + k0 + s * 8);
    int4 b1v = *(const int4*)(yb + (size_t)rB1 * N_ + k0 + s * 8);
    __syncthreads();
    *(int4*)(lA + r2 * LDSTR + s * 8)        = a0;
    *(int4*)(lA + (r2 + 32) * LDSTR + s * 8) = a1;
    *(int4*)(lB + r2 * LDSTR + s * 8)        = b0v;
    *(int4*)(lB + (r2 + 32) * LDSTR + s * 8) = b1v;
    __syncthreads();
    #pragma unroll
    for (int kk = 0; kk < 2; kk++){
      bf16x8 af0 = *(const bf16x8*)(lA + (wm * 32 + l16)      * LDSTR + kk * 32 + quad * 8);
      bf16x8 af1 = *(const bf16x8*)(lA + (wm * 32 + 16 + l16) * LDSTR + kk * 32 + quad * 8);
      bf16x8 bf0 = *(const bf16x8*)(lB + (wn * 32 + l16)      * LDSTR + kk * 32 + quad * 8);
      bf16x8 bf1 = *(const bf16x8*)(lB + (wn * 32 + 16 + l16) * LDSTR + kk * 32 + quad * 8);
      acc[0][0] = __builtin_amdgcn_mfma_f32_16x16x32_bf16(af0, bf0, acc[0][0], 0, 0, 0);
      acc[0][1] = __builtin_amdgcn_mfma_f32_16x16x32_bf16(af0, bf1, acc[0][1], 0, 0, 0);
      acc[1][0] = __builtin_amdgcn_mfma_f32_16x16x32_bf16(af1, bf0, acc[1][0], 0, 0, 0);
      acc[1][1] = __builtin_amdgcn_mfma_f32_16x16x32_bf16(af1, bf1, acc[1][1], 0, 0, 0);
    }
  }
  float* pp = partials + ((size_t)ks * (B_ * NTILE) + bt) * 4096 + t * 16;
  #pragma unroll
  for (int im = 0; im < 2; im++)
    #pragma unroll
    for (int in = 0; in < 2; in++)
      *(f32x4*)(pp + 4 * (im * 2 + in)) = acc[im][in];
}

// fold KSPLIT partials, write C (+ mirror), per-block minmax -> scr
__global__ void __launch_bounds__(256) corr_reduce(const float* __restrict__ partials,
                                                   float* __restrict__ out,
                                                   float* __restrict__ scr){
  int bt = blockIdx.x;
  int b = bt / NTILE, tile = bt - b * NTILE;
  int ti = TI_[tile], tj = TJ_[tile];
  bool diag = (ti == tj);
  int t = threadIdx.x;
  int wv = t >> 6, ln = t & 63;
  int wm = wv & 1, wn = wv >> 1;
  int quad = ln >> 4, l16 = ln & 15;
  f32x4 acc[2][2];
  #pragma unroll
  for (int im = 0; im < 2; im++)
    #pragma unroll
    for (int in = 0; in < 2; in++){
      f32x4 a = {0.f, 0.f, 0.f, 0.f};
      #pragma unroll
      for (int ks = 0; ks < KSPLIT; ks++)
        a += *(const f32x4*)(partials + ((size_t)ks * (B_ * NTILE) + bt) * 4096
                             + t * 16 + 4 * (im * 2 + in));
      acc[im][in] = a;
    }
  float mn = INFINITY, mx = -INFINITY;
  float* ov = out + ((size_t)b * 3 + 2) * PIX;
  #pragma unroll
  for (int im = 0; im < 2; im++)
    #pragma unroll
    for (int in = 0; in < 2; in++){
      int gi0 = ti * 64 + wm * 32 + im * 16 + quad * 4;
      int gj  = tj * 64 + wn * 32 + in * 16 + l16;
      #pragma unroll
      for (int rg = 0; rg < 4; rg++){
        int gi = gi0 + rg;
        if (gi < IMG && gj < IMG){
          float v = acc[im][in][rg];
          ov[gi * IMG + gj] = v;
          mn = fminf(mn, v); mx = fmaxf(mx, v);
        }
      }
      if (!diag && gj < IMG && gi0 < IMG){   // mirrored tile, packed store
        float4 tv;
        tv.x = acc[im][in][0]; tv.y = acc[im][in][1];
        tv.z = acc[im][in][2]; tv.w = acc[im][in][3];
        *(float4*)(ov + gj * IMG + gi0) = tv;
      }
    }
  #pragma unroll
  for (int o = 32; o; o >>= 1){
    mn = fminf(mn, __shfl_down(mn, o)); mx = fmaxf(mx, __shfl_down(mx, o));
  }
  __shared__ float red[4][2];
  if (ln == 0){ red[wv][0] = mn; red[wv][1] = mx; }
  __syncthreads();
  if (t == 0){
    scr[bt * 2 + 0] = fminf(fminf(red[0][0], red[1][0]), fminf(red[2][0], red[3][0]));
    scr[bt * 2 + 1] = fmaxf(fmaxf(red[0][1], red[1][1]), fmaxf(red[2][1], red[3][1]));
  }
}

// ---------------- final minmax reduce ---------------------------------------
__global__ void __launch_bounds__(256) reduce_slots(const float* __restrict__ sv_scr,
                                                    const float* __restrict__ corr_scr,
                                                    float* __restrict__ slots){
  int t = threadIdx.x;
  float tmn = sv_scr[4*t+0], tmx = sv_scr[4*t+1];
  float smn = sv_scr[4*t+2], smx = sv_scr[4*t+3];
  float cmn = INFINITY, cmx = -INFINITY;
  for (int idx = t; idx < B_ * NTILE; idx += 256){
    cmn = fminf(cmn, corr_scr[2*idx]);
    cmx = fmaxf(cmx, corr_scr[2*idx+1]);
  }
  #pragma unroll
  for (int o = 32; o; o >>= 1){
    tmn = fminf(tmn, __shfl_down(tmn, o)); tmx = fmaxf(tmx, __shfl_down(tmx, o));
    smn = fminf(smn, __shfl_down(smn, o)); smx = fmaxf(smx, __shfl_down(smx, o));
    cmn = fminf(cmn, __shfl_down(cmn, o)); cmx = fmaxf(cmx, __shfl_down(cmx, o));
  }
  __shared__ float red[4][6];
  int wv = t >> 6, ln = t & 63;
  if (ln == 0){
    red[wv][0]=tmn; red[wv][1]=tmx; red[wv][2]=smn;
    red[wv][3]=smx; red[wv][4]=cmn; red[wv][5]=cmx;
  }
  __syncthreads();
  if (t == 0){
    slots[0] = fminf(fminf(red[0][0],red[1][0]), fminf(red[2][0],red[3][0]));
    slots[1] = fmaxf(fmaxf(red[0][1],red[1][1]), fmaxf(red[2][1],red[3][1]));
    slots[2] = fminf(fminf(red[0][2],red[1][2]), fminf(red[2][2],red[3][2]));
    slots[3] = fmaxf(fmaxf(red[0][3],red[1][3]), fmaxf(red[2][3],red[3][3]));
    slots[4] = fminf(fminf(red[0][4],red[1][4]), fminf(red[2][4],red[3][4]));
    slots[5] = fmaxf(fmaxf(red[0][5],red[1][5]), fmaxf(red[2][5],red[3][5]));
  }
}

// ---------------- final: recompute small views normalized + normalize corr ---
__global__ void __launch_bounds__(256) final_write(const float* __restrict__ meanv,
                                                   const float* __restrict__ colmean,
                                                   float* __restrict__ out,
                                                   const float* __restrict__ slots){
  int g = blockIdx.x * 256 + threadIdx.x;
  float tmn = slots[0], tmx = slots[1];
  float smn = slots[2], smx = slots[3];
  int b = g / PIX, p = g - b * PIX;
  int i = p / IMG, j = p - i * IMG;
  float tv = bilin(meanv   + b * E_, 23, E_, i, j);
  float sv = bilin(colmean + b * N_, 64, N_, i, j);
  float td = tmx - tmn, sd = smx - smn;
  out[((size_t)b * 3 + 0) * PIX + p] = (td < 1e-8f) ? 0.f : (tv - tmn) / (td + 1e-8f);
  out[((size_t)b * 3 + 1) * PIX + p] = (sd < 1e-8f) ? 0.f : (sv - smn) / (sd + 1e-8f);
  if (g < B_ * PIX / 4){           // uniform per block: B*PIX/4 = 1568*256
    float cmn = slots[4], cmx = slots[5];
    float cd = cmx - cmn;
    float inv = 1.f / (cd + 1e-8f);
    bool z = cd < 1e-8f;
    int c = g * 4;
    int bb = c / PIX, pp = c - bb * PIX;   // PIX % 4 == 0 -> uniform bb in float4
    float* oc = out + ((size_t)bb * 3 + 2) * PIX + pp;
    float4 v = *(float4*)oc;
    v.x = z ? 0.f : (v.x - cmn) * inv;
    v.y = z ? 0.f : (v.y - cmn) * inv;
    v.z = z ? 0.f : (v.z - cmn) * inv;
    v.w = z ? 0.f : (v.w - cmn) * inv;
    *(float4*)oc = v;
  }
}

extern "C" void kernel_launch(void* const* d_in, const int* in_sizes, int n_in,
                              void* d_out, int out_size, void* d_ws, size_t ws_size,
                              hipStream_t stream){
  const float* x = (const float*)d_in[0];
  float* out = (float*)d_out;
  char* ws = (char*)d_ws;
  float* slots    = (float*)(ws + 0);                     // 6 f (pad 256 B)
  float* meanv    = (float*)(ws + 256);                   // B*E f
  float* colmean  = meanv + B_ * E_;                      // B*N f
  float* colpart  = colmean + B_ * N_;                    // B*32*N f (16 MB)
  float* sv_scr   = colpart + (size_t)B_ * NCHUNK * N_;   // SV_BLOCKS*4 f
  float* corr_scr = sv_scr + SV_BLOCKS * 4;               // 640 f
  size_t y_off = ((size_t)((char*)(corr_scr + B_ * NTILE * 2) - ws) + 255) & ~(size_t)255;
  ushort* y = (ushort*)(ws + y_off);                      // B*224*4096 bf16 (58.7 MB)
  size_t p_off = (y_off + (size_t)B_ * IMG * N_ * 2 + 255) & ~(size_t)255;
  float* partials = (float*)(ws + p_off);                 // KSPLIT*B*NTILE*4096 f (10.5 MB)

  hipLaunchKernelGGL(stats_y, dim3(B_ * NCHUNK), dim3(256), 0, stream,
                     x, meanv, colpart, y);
  hipLaunchKernelGGL(corr_gemm_sk, dim3(KSPLIT * B_ * NTILE), dim3(256), 0, stream,
                     y, partials);
  hipLaunchKernelGGL(corr_reduce, dim3(B_ * NTILE), dim3(256), 0, stream,
                     partials, out, corr_scr);
  hipLaunchKernelGGL(col_finalize, dim3(B_ * 16), dim3(256), 0, stream,
                     colpart, colmean);
  hipLaunchKernelGGL(sv_minmax, dim3(SV_BLOCKS), dim3(256), 0, stream,
                     meanv, colmean, sv_scr);
  hipLaunchKernelGGL(reduce_slots, dim3(1), dim3(256), 0, stream,
                     sv_scr, corr_scr, slots);
  hipLaunchKernelGGL(final_write, dim3(B_ * PIX / 256), dim3(256), 0, stream,
                     meanv, colmean, out, slots);
}

// Round 6
// 444.415 us; speedup vs baseline: 1.2610x; 1.0020x over previous
//
#include <hip/hip_runtime.h>
#include <hip/hip_bf16.h>
#include <math.h>

#define IMG 224
#define PIX (IMG*IMG)   // 50176
#define B_ 32
#define E_ 512
#define N_ 4096
#define SC_ ((float)(512.0/224.0))
#define RPB 16          // rows per stats block
#define NCHUNK 32       // E_/RPB
#define KSPLIT 2
#define KLEN (N_/KSPLIT)  // 2048
#define NTILE 10          // symmetric 64x64 tiles of 224x224
#define LDSTR 72

typedef __attribute__((ext_vector_type(8))) short bf16x8;
typedef __attribute__((ext_vector_type(4))) float f32x4;

__device__ inline unsigned short f2bf(float f){
  unsigned u = __float_as_uint(f);
  unsigned r = (u + 0x7FFFu + ((u >> 16) & 1u)) >> 16;  // RNE
  return (unsigned short)r;
}

// ---------- dispatch 1: row stats + column partials + inline y emission ----------
__global__ void __launch_bounds__(256) stats_y(const float* __restrict__ x,
                                               float* __restrict__ meanv,
                                               float* __restrict__ colpart,
                                               ushort* __restrict__ y){
  int b = blockIdx.x >> 5, chunk = blockIdx.x & 31;
  int e0 = chunk << 4;
  int t = threadIdx.x;
  __shared__ short sInv[512];   // src row r0 -> output row i (or -1)
  __shared__ float sW[224];     // interp weight per output row
  __shared__ float red[2][16];  // parity-buffered reduction slab
  sInv[t] = -1; sInv[t + 256] = -1;
  __syncthreads();
  if (t < 224){
    float r = fmaxf(((float)t + 0.5f) * SC_ - 0.5f, 0.f);
    int r0 = min((int)r, E_ - 1);
    sW[t] = r - (float)r0;
    sInv[r0] = (short)t;        // scale > 2 => at most one i per r0
  }
  __syncthreads();

  float cur[16], prev[16], nxt[16], csum[16];
  #pragma unroll
  for (int j = 0; j < 16; j++){ csum[j] = 0.f; prev[j] = 0.f; }
  const float4* row0 = (const float4*)(x + ((size_t)b * E_ + e0) * N_);
  #pragma unroll
  for (int k = 0; k < 4; k++) *(float4*)(cur + 4 * k) = row0[t + 256 * k];
  float pmu = 0.f, prn = 0.f;

  for (int idx = 0; idx <= RPB; idx++){
    int e = e0 + idx;
    if (e >= E_) break;
    bool hasNext = (idx < RPB) && (e + 1 < E_);
    if (hasNext){
      const float4* nr = (const float4*)(x + ((size_t)b * E_ + e + 1) * N_);
      #pragma unroll
      for (int k = 0; k < 4; k++) *(float4*)(nxt + 4 * k) = nr[t + 256 * k];
    }
    float s = 0.f, ss = 0.f;
    #pragma unroll
    for (int j = 0; j < 16; j++){ s += cur[j]; ss += cur[j] * cur[j]; }
    #pragma unroll
    for (int o = 32; o; o >>= 1){ s += __shfl_down(s, o); ss += __shfl_down(ss, o); }
    int wv = t >> 6, ln = t & 63, p = idx & 1;
    if (ln == 0){ red[p][wv] = s; red[p][8 + wv] = ss; }
    __syncthreads();    // single barrier per row
    float S  = red[p][0] + red[p][1] + red[p][2] + red[p][3];
    float SS = red[p][8] + red[p][9] + red[p][10] + red[p][11];
    float mu = S * (1.f / N_);
    float var = fmaxf(SS - S * S * (1.f / N_), 0.f);
    float rn = 1.f / (sqrtf(var) + 1e-8f);
    if (idx < RPB){
      #pragma unroll
      for (int j = 0; j < 16; j++) csum[j] += cur[j];
      if (t == 0) meanv[b * E_ + e] = mu;
    }
    if (idx >= 1){
      int i = sInv[e - 1];
      if (i >= 0){
        float w = sW[i];
        float a0 = (1.f - w) * prn, a1 = w * rn;
        float cc = -(a0 * pmu + a1 * mu);
        ushort* yo = y + ((size_t)b * IMG + i) * N_;
        #pragma unroll
        for (int k = 0; k < 4; k++){
          union { ushort u[4]; int2 v; } pk;
          #pragma unroll
          for (int j = 0; j < 4; j++)
            pk.u[j] = f2bf(a0 * prev[4*k+j] + a1 * cur[4*k+j] + cc);
          *(int2*)(yo + 1024 * k + 4 * t) = pk.v;
        }
      }
    }
    pmu = mu; prn = rn;
    #pragma unroll
    for (int j = 0; j < 16; j++){ prev[j] = cur[j]; if (hasNext) cur[j] = nxt[j]; }
  }
  float* cp = colpart + ((size_t)(b * NCHUNK + chunk)) * N_;
  #pragma unroll
  for (int k = 0; k < 4; k++) *(float4*)(cp + 1024 * k + 4 * t) = *(float4*)(csum + 4 * k);
}

// ---------------- bilinear helpers -----------------------------------------
__device__ inline float grid_val(const float* v, int gs, int n, int r, int c){
  int idx = r * gs + c;
  return (idx < n) ? v[idx] : 0.f;
}
__device__ inline float bilin(const float* v, int gs, int n, int i, int j){
  float sc = (float)((double)gs / 224.0);
  float r = fmaxf(((float)i + 0.5f) * sc - 0.5f, 0.f);
  float c = fmaxf(((float)j + 0.5f) * sc - 0.5f, 0.f);
  int r0 = min((int)r, gs - 1), c0 = min((int)c, gs - 1);
  int r1 = min(r0 + 1, gs - 1), c1 = min(c0 + 1, gs - 1);
  float wr = r - (float)r0, wc = c - (float)c0;
  float v00 = grid_val(v, gs, n, r0, c0), v10 = grid_val(v, gs, n, r1, c0);
  float v01 = grid_val(v, gs, n, r0, c1), v11 = grid_val(v, gs, n, r1, c1);
  float ra = v00 * (1.f - wr) + v10 * wr;
  float rb = v01 * (1.f - wr) + v11 * wr;
  return ra * (1.f - wc) + rb * wc;
}

__device__ const int TI_[NTILE] = {0,0,0,0,1,1,1,2,2,3};
__device__ const int TJ_[NTILE] = {0,1,2,3,1,2,3,2,3,3};

// ---------- dispatch 2: corr GEMM (blocks 0-639) || col_finalize (640-767) ----------
// GEMM mapping: XCD-pinned as in the proven 445-us version. The extra 128
// colfin blocks only read colpart (ready: previous dispatch) and write colmean
// (consumed: next dispatch) -> no intra-dispatch dependency.
__global__ void __launch_bounds__(256) gemm_colfin(const ushort* __restrict__ y,
                                                   float* __restrict__ partials,
                                                   const float* __restrict__ colpart,
                                                   float* __restrict__ colmean){
  int bid = blockIdx.x;
  int t = threadIdx.x;
  if (bid >= 640){
    // col_finalize: 512 units over 128 blocks
    for (int u = bid - 640; u < 512; u += 128){
      int b = u >> 4;
      int n = ((u & 15) << 8) + t;
      float s = 0.f;
      #pragma unroll
      for (int c = 0; c < NCHUNK; c++) s += colpart[((size_t)(b * NCHUNK + c)) * N_ + n];
      colmean[b * N_ + n] = s * (1.f / E_);
    }
    return;
  }
  int xcd  = bid & 7;
  int slot = bid >> 3;                 // 0..79 within this XCD
  int b    = (xcd << 2) + (slot / 20); // 4 batches per XCD
  int rem  = slot % 20;
  int ks   = rem / 10;
  int tile = rem - ks * 10;
  int bt   = b * NTILE + tile;
  int ti = TI_[tile], tj = TJ_[tile];
  const ushort* yb = y + (size_t)b * IMG * N_ + (size_t)ks * KLEN;
  __shared__ ushort lA[64 * LDSTR];
  __shared__ ushort lB[64 * LDSTR];
  int wv = t >> 6, ln = t & 63;
  int wm = wv & 1, wn = wv >> 1;
  int quad = ln >> 4, l16 = ln & 15;
  f32x4 acc[2][2] = {};
  int s = t & 7, r2 = t >> 3;
  int rA0 = min(ti * 64 + r2,      223), rA1 = min(ti * 64 + r2 + 32, 223);
  int rB0 = min(tj * 64 + r2,      223), rB1 = min(tj * 64 + r2 + 32, 223);
  for (int k0 = 0; k0 < KLEN; k0 += 64){
    int4 a0 = *(const int4*)(yb + (size_t)rA0 * N_ + k0 + s * 8);
    int4 a1 = *(const int4*)(yb + (size_t)rA1 * N_ + k0 + s * 8);
    int4 b0v = *(const int4*)(yb + (size_t)rB0 * N_ + k0 + s * 8);
    int4 b1v = *(const int4*)(yb + (size_t)rB1 * N_ + k0 + s * 8);
    __syncthreads();
    *(int4*)(lA + r2 * LDSTR + s * 8)        = a0;
    *(int4*)(lA + (r2 + 32) * LDSTR + s * 8) = a1;
    *(int4*)(lB + r2 * LDSTR + s * 8)        = b0v;
    *(int4*)(lB + (r2 + 32) * LDSTR + s * 8) = b1v;
    __syncthreads();
    #pragma unroll
    for (int kk = 0; kk < 2; kk++){
      bf16x8 af0 = *(const bf16x8*)(lA + (wm * 32 + l16)      * LDSTR + kk * 32 + quad * 8);
      bf16x8 af1 = *(const bf16x8*)(lA + (wm * 32 + 16 + l16) * LDSTR + kk * 32 + quad * 8);
      bf16x8 bf0 = *(const bf16x8*)(lB + (wn * 32 + l16)      * LDSTR + kk * 32 + quad * 8);
      bf16x8 bf1 = *(const bf16x8*)(lB + (wn * 32 + 16 + l16) * LDSTR + kk * 32 + quad * 8);
      acc[0][0] = __builtin_amdgcn_mfma_f32_16x16x32_bf16(af0, bf0, acc[0][0], 0, 0, 0);
      acc[0][1] = __builtin_amdgcn_mfma_f32_16x16x32_bf16(af0, bf1, acc[0][1], 0, 0, 0);
      acc[1][0] = __builtin_amdgcn_mfma_f32_16x16x32_bf16(af1, bf0, acc[1][0], 0, 0, 0);
      acc[1][1] = __builtin_amdgcn_mfma_f32_16x16x32_bf16(af1, bf1, acc[1][1], 0, 0, 0);
    }
  }
  float* pp = partials + ((size_t)ks * (B_ * NTILE) + bt) * 4096 + t * 16;
  #pragma unroll
  for (int im = 0; im < 2; im++)
    #pragma unroll
    for (int in = 0; in < 2; in++)
      *(f32x4*)(pp + 4 * (im * 2 + in)) = acc[im][in];
}

// ---------- dispatch 3: corr_reduce (blocks 0-319) || sv_minmax (320-575) ----------
__global__ void __launch_bounds__(256) reduce_sv(const float* __restrict__ partials,
                                                 const float* __restrict__ meanv,
                                                 const float* __restrict__ colmean,
                                                 float* __restrict__ out,
                                                 float* __restrict__ corr_scr,
                                                 float* __restrict__ sv_scr){
  int bid = blockIdx.x;
  int t = threadIdx.x;
  int wv = t >> 6, ln = t & 63;
  __shared__ float red[4][4];
  if (bid < B_ * NTILE){
    int bt = bid;
    int b = bt / NTILE, tile = bt - b * NTILE;
    int ti = TI_[tile], tj = TJ_[tile];
    bool diag = (ti == tj);
    int wm = wv & 1, wn = wv >> 1;
    int quad = ln >> 4, l16 = ln & 15;
    f32x4 acc[2][2];
    #pragma unroll
    for (int im = 0; im < 2; im++)
      #pragma unroll
      for (int in = 0; in < 2; in++){
        f32x4 a = {0.f, 0.f, 0.f, 0.f};
        #pragma unroll
        for (int ks = 0; ks < KSPLIT; ks++)
          a += *(const f32x4*)(partials + ((size_t)ks * (B_ * NTILE) + bt) * 4096
                               + t * 16 + 4 * (im * 2 + in));
        acc[im][in] = a;
      }
    float mn = INFINITY, mx = -INFINITY;
    float* ov = out + ((size_t)b * 3 + 2) * PIX;
    #pragma unroll
    for (int im = 0; im < 2; im++)
      #pragma unroll
      for (int in = 0; in < 2; in++){
        int gi0 = ti * 64 + wm * 32 + im * 16 + quad * 4;
        int gj  = tj * 64 + wn * 32 + in * 16 + l16;
        #pragma unroll
        for (int rg = 0; rg < 4; rg++){
          int gi = gi0 + rg;
          if (gi < IMG && gj < IMG){
            float v = acc[im][in][rg];
            ov[gi * IMG + gj] = v;
            mn = fminf(mn, v); mx = fmaxf(mx, v);
          }
        }
        if (!diag && gj < IMG && gi0 < IMG){   // mirrored tile, packed store
          float4 tv;
          tv.x = acc[im][in][0]; tv.y = acc[im][in][1];
          tv.z = acc[im][in][2]; tv.w = acc[im][in][3];
          *(float4*)(ov + gj * IMG + gi0) = tv;
        }
      }
    #pragma unroll
    for (int o = 32; o; o >>= 1){
      mn = fminf(mn, __shfl_down(mn, o)); mx = fmaxf(mx, __shfl_down(mx, o));
    }
    if (ln == 0){ red[wv][0] = mn; red[wv][1] = mx; }
    __syncthreads();
    if (t == 0){
      corr_scr[bt * 2 + 0] = fminf(fminf(red[0][0], red[1][0]), fminf(red[2][0], red[3][0]));
      corr_scr[bt * 2 + 1] = fmaxf(fmaxf(red[0][1], red[1][1]), fmaxf(red[2][1], red[3][1]));
    }
  } else {
    int vb = bid - B_ * NTILE;   // virtual sv block 0..255
    float tmn = INFINITY, tmx = -INFINITY, smn = INFINITY, smx = -INFINITY;
    for (int g = vb * 256 + t; g < B_ * PIX; g += 256 * 256){
      int b = g / PIX, p = g - b * PIX;
      int i = p / IMG, j = p - i * IMG;
      float tv = bilin(meanv   + b * E_, 23, E_, i, j);
      float sv = bilin(colmean + b * N_, 64, N_, i, j);
      tmn = fminf(tmn, tv); tmx = fmaxf(tmx, tv);
      smn = fminf(smn, sv); smx = fmaxf(smx, sv);
    }
    #pragma unroll
    for (int o = 32; o; o >>= 1){
      tmn = fminf(tmn, __shfl_down(tmn, o)); tmx = fmaxf(tmx, __shfl_down(tmx, o));
      smn = fminf(smn, __shfl_down(smn, o)); smx = fmaxf(smx, __shfl_down(smx, o));
    }
    if (ln == 0){ red[wv][0] = tmn; red[wv][1] = tmx; red[wv][2] = smn; red[wv][3] = smx; }
    __syncthreads();
    if (t == 0){
      sv_scr[vb * 4 + 0] = fminf(fminf(red[0][0], red[1][0]), fminf(red[2][0], red[3][0]));
      sv_scr[vb * 4 + 1] = fmaxf(fmaxf(red[0][1], red[1][1]), fmaxf(red[2][1], red[3][1]));
      sv_scr[vb * 4 + 2] = fminf(fminf(red[0][2], red[1][2]), fminf(red[2][2], red[3][2]));
      sv_scr[vb * 4 + 3] = fmaxf(fmaxf(red[0][3], red[1][3]), fmaxf(red[2][3], red[3][3]));
    }
  }
}

// ---------- dispatch 4: redundant slots reduce + final writes ----------
// Each of the 6272 blocks reduces the tiny scr arrays (L2-resident, ~3.5 KB)
// in-register, then writes its 256 pixels of views 0/1 and normalizes view 2.
__global__ void __launch_bounds__(256) final_write(const float* __restrict__ meanv,
                                                   const float* __restrict__ colmean,
                                                   float* __restrict__ out,
                                                   const float* __restrict__ sv_scr,
                                                   const float* __restrict__ corr_scr){
  int t = threadIdx.x;
  int wv = t >> 6, ln = t & 63;
  __shared__ float red6[4][6];
  __shared__ float slot6[6];
  {
    float tmn = sv_scr[4*t+0], tmx = sv_scr[4*t+1];
    float smn = sv_scr[4*t+2], smx = sv_scr[4*t+3];
    float cmn = INFINITY, cmx = -INFINITY;
    for (int idx = t; idx < B_ * NTILE; idx += 256){
      cmn = fminf(cmn, corr_scr[2*idx]);
      cmx = fmaxf(cmx, corr_scr[2*idx+1]);
    }
    #pragma unroll
    for (int o = 32; o; o >>= 1){
      tmn = fminf(tmn, __shfl_down(tmn, o)); tmx = fmaxf(tmx, __shfl_down(tmx, o));
      smn = fminf(smn, __shfl_down(smn, o)); smx = fmaxf(smx, __shfl_down(smx, o));
      cmn = fminf(cmn, __shfl_down(cmn, o)); cmx = fmaxf(cmx, __shfl_down(cmx, o));
    }
    if (ln == 0){
      red6[wv][0]=tmn; red6[wv][1]=tmx; red6[wv][2]=smn;
      red6[wv][3]=smx; red6[wv][4]=cmn; red6[wv][5]=cmx;
    }
    __syncthreads();
    if (t == 0){
      slot6[0] = fminf(fminf(red6[0][0],red6[1][0]), fminf(red6[2][0],red6[3][0]));
      slot6[1] = fmaxf(fmaxf(red6[0][1],red6[1][1]), fmaxf(red6[2][1],red6[3][1]));
      slot6[2] = fminf(fminf(red6[0][2],red6[1][2]), fminf(red6[2][2],red6[3][2]));
      slot6[3] = fmaxf(fmaxf(red6[0][3],red6[1][3]), fmaxf(red6[2][3],red6[3][3]));
      slot6[4] = fminf(fminf(red6[0][4],red6[1][4]), fminf(red6[2][4],red6[3][4]));
      slot6[5] = fmaxf(fmaxf(red6[0][5],red6[1][5]), fmaxf(red6[2][5],red6[3][5]));
    }
    __syncthreads();
  }
  float tmn = slot6[0], tmx = slot6[1];
  float smn = slot6[2], smx = slot6[3];
  float cmn = slot6[4], cmx = slot6[5];

  int g = blockIdx.x * 256 + t;
  int b = g / PIX, p = g - b * PIX;
  int i = p / IMG, j = p - i * IMG;
  float tv = bilin(meanv   + b * E_, 23, E_, i, j);
  float sv = bilin(colmean + b * N_, 64, N_, i, j);
  float td = tmx - tmn, sd = smx - smn;
  out[((size_t)b * 3 + 0) * PIX + p] = (td < 1e-8f) ? 0.f : (tv - tmn) / (td + 1e-8f);
  out[((size_t)b * 3 + 1) * PIX + p] = (sd < 1e-8f) ? 0.f : (sv - smn) / (sd + 1e-8f);
  if (g < B_ * PIX / 4){           // uniform per block: B*PIX/4 = 1568*256
    float cd = cmx - cmn;
    float inv = 1.f / (cd + 1e-8f);
    bool z = cd < 1e-8f;
    int c = g * 4;
    int bb = c / PIX, pp = c - bb * PIX;   // PIX % 4 == 0 -> uniform bb in float4
    float* oc = out + ((size_t)bb * 3 + 2) * PIX + pp;
    float4 v = *(float4*)oc;
    v.x = z ? 0.f : (v.x - cmn) * inv;
    v.y = z ? 0.f : (v.y - cmn) * inv;
    v.z = z ? 0.f : (v.z - cmn) * inv;
    v.w = z ? 0.f : (v.w - cmn) * inv;
    *(float4*)oc = v;
  }
}

extern "C" void kernel_launch(void* const* d_in, const int* in_sizes, int n_in,
                              void* d_out, int out_size, void* d_ws, size_t ws_size,
                              hipStream_t stream){
  const float* x = (const float*)d_in[0];
  float* out = (float*)d_out;
  char* ws = (char*)d_ws;
  float* meanv    = (float*)(ws + 256);                   // B*E f
  float* colmean  = meanv + B_ * E_;                      // B*N f
  float* colpart  = colmean + B_ * N_;                    // B*32*N f (16 MB)
  float* sv_scr   = colpart + (size_t)B_ * NCHUNK * N_;   // 256*4 f
  float* corr_scr = sv_scr + 256 * 4;                     // 640 f
  size_t y_off = ((size_t)((char*)(corr_scr + B_ * NTILE * 2) - ws) + 255) & ~(size_t)255;
  ushort* y = (ushort*)(ws + y_off);                      // B*224*4096 bf16 (58.7 MB)
  size_t p_off = (y_off + (size_t)B_ * IMG * N_ * 2 + 255) & ~(size_t)255;
  float* partials = (float*)(ws + p_off);                 // KSPLIT*B*NTILE*4096 f (10.5 MB)

  hipLaunchKernelGGL(stats_y, dim3(B_ * NCHUNK), dim3(256), 0, stream,
                     x, meanv, colpart, y);
  hipLaunchKernelGGL(gemm_colfin, dim3(768), dim3(256), 0, stream,
                     y, partials, colpart, colmean);
  hipLaunchKernelGGL(reduce_sv, dim3(B_ * NTILE + 256), dim3(256), 0, stream,
                     partials, meanv, colmean, out, corr_scr, sv_scr);
  hipLaunchKernelGGL(final_write, dim3(B_ * PIX / 256), dim3(256), 0, stream,
                     meanv, colmean, out, sv_scr, corr_scr);
}